// Round 1
// baseline (42.349 us; speedup 1.0000x reference)
//
#include <hip/hip_runtime.h>
#include <math.h>

#define CUTOFF 5.0f
#define BLOCK 256

__global__ __launch_bounds__(BLOCK) void graph_edges_kernel(
    const float* __restrict__ coords,
    const int*   __restrict__ esrc,
    const int*   __restrict__ edst,
    float*       __restrict__ out,
    int E)
{
    __shared__ float buf[BLOCK * 5];
    const float PI_OVER_C = 3.14159265358979323846f / CUTOFF;
    const int t = threadIdx.x;

    for (int base = blockIdx.x * BLOCK; base < E; base += gridDim.x * BLOCK) {
        int e = base + t;
        float vx = 0.f, vy = 0.f, vz = 0.f, d = 0.f, sw = 0.f;
        if (e < E) {
            int s  = esrc[e];
            int dd = edst[e];
            float sx = coords[3 * s + 0];
            float sy = coords[3 * s + 1];
            float sz = coords[3 * s + 2];
            float tx = coords[3 * dd + 0];
            float ty = coords[3 * dd + 1];
            float tz = coords[3 * dd + 2];
            vx = tx - sx;
            vy = ty - sy;
            vz = tz - sz;
            d = sqrtf(vx * vx + vy * vy + vz * vz);
            sw = (d < CUTOFF) ? (0.5f * __cosf(d * PI_OVER_C) + 0.5f) : 0.0f;
        }
        // stage in LDS: stride-5 word writes, gcd(5,32)=1 -> <=2-way bank alias (free)
        buf[t * 5 + 0] = vx;
        buf[t * 5 + 1] = vy;
        buf[t * 5 + 2] = vz;
        buf[t * 5 + 3] = d;
        buf[t * 5 + 4] = sw;
        __syncthreads();
        // coalesced contiguous store of this block's [BLOCK,5] chunk
        int remaining = E - base;
        int n = (remaining < BLOCK ? remaining : BLOCK) * 5;
        int ob = base * 5;
        for (int k = t; k < n; k += BLOCK) {
            out[ob + k] = buf[k];
        }
        __syncthreads();  // protect buf before next iteration overwrites it
    }
}

extern "C" void kernel_launch(void* const* d_in, const int* in_sizes, int n_in,
                              void* d_out, int out_size, void* d_ws, size_t ws_size,
                              hipStream_t stream) {
    const float* coords = (const float*)d_in[0];
    const int*   esrc   = (const int*)d_in[1];
    const int*   edst   = (const int*)d_in[2];
    float*       out    = (float*)d_out;

    int E = in_sizes[1];  // number of edges
    int blocks_needed = (E + BLOCK - 1) / BLOCK;
    int grid = blocks_needed < 2048 ? blocks_needed : 2048;  // 256 CU x 8 blocks, grid-stride rest

    graph_edges_kernel<<<grid, BLOCK, 0, stream>>>(coords, esrc, edst, out, E);
}